// Round 6
// baseline (114.661 us; speedup 1.0000x reference)
//
#include <hip/hip_runtime.h>
#include <hip/hip_bf16.h>

#define B_DIM   1024
#define N_DIM   2048
#define G_DIM   32
#define H1_DIM  2048
#define H2_DIM  512
#define BN_EPS  1e-5f
#define SLOPE   0.05f

typedef short v8s __attribute__((ext_vector_type(8)));
typedef float v4f __attribute__((ext_vector_type(4)));

__device__ __forceinline__ float lrelu_f(float v) { return v >= 0.f ? v : SLOPE * v; }
__device__ __forceinline__ float bf2f(unsigned short u) {
    union { unsigned int i; float f; } c; c.i = ((unsigned int)u) << 16; return c.f;
}
__device__ __forceinline__ unsigned short f2bf(float f) {
    __hip_bfloat16 h = __float2bfloat16(f);
    return *(unsigned short*)&h;
}

// async global->LDS, 16B per lane, linear LDS dest (wave-uniform base + lane*16)
#define GLOAD_LDS16(gp, lp)                                                              \
    __builtin_amdgcn_global_load_lds(                                                    \
        (const __attribute__((address_space(1))) unsigned int*)(gp),                     \
        (__attribute__((address_space(3))) unsigned int*)(lp), 16, 0, 0)

// ================================================================ prep kernel
// bid < 2048          : group_linear  g[b][n] = lrelu(dot(x[b,n*32:], Wg[n]) + bg[n])
// 2048 <= bid < 3072  : W1 [N][H1] -> W1T [H1][N] bf16, rows scaled by softmax(att_w)
// bid >= 3072         : W2 [H1][H2] -> W2T [H2][H1] bf16
// group_linear and the transposes are data-independent; merging keeps HBM
// saturated through the whole prep phase and removes one launch gap.
__global__ __launch_bounds__(256) void prep_kernel(
        const float* __restrict__ x, const float* __restrict__ Wg,
        const float* __restrict__ bg, __hip_bfloat16* __restrict__ g,
        const float* __restrict__ W1, const float* __restrict__ W2,
        const float* __restrict__ aw,
        __hip_bfloat16* __restrict__ W1T, __hip_bfloat16* __restrict__ W2T) {
    __shared__ float tile[64][65];
    __shared__ float red[8];
    __shared__ float scl[64];
    int t = threadIdx.x;
    int bid = blockIdx.x;

    if (bid < 2048) {
        // ---------------- group_linear: 2 lanes per group, coalesced x reads
        int brow = bid >> 4;              // 128 brows x 8 batch rows
        int seg = bid & 15;               // 16 segs x 128 groups
        int gl = t >> 1, half = t & 1;
        int n = seg * 128 + gl;
        float4 wv[4];
        const float4* wsrc = (const float4*)(Wg + (size_t)n * 32 + half * 16);
#pragma unroll
        for (int q = 0; q < 4; ++q) wv[q] = wsrc[q];
        float bgv = bg[n];
#pragma unroll
        for (int bb = 0; bb < 8; ++bb) {
            int b = brow * 8 + bb;
            const float4* xr = (const float4*)(x + (size_t)b * (N_DIM * G_DIM) +
                                               (size_t)n * 32 + half * 16);
            float s = 0.f;
#pragma unroll
            for (int q = 0; q < 4; ++q) {
                float4 v = xr[q];
                s += v.x * wv[q].x + v.y * wv[q].y + v.z * wv[q].z + v.w * wv[q].w;
            }
            s += __shfl_xor(s, 1, 64);
            if (half == 0)
                g[(size_t)b * N_DIM + n] = __float2bfloat16(lrelu_f(s + bgv));
        }
        return;
    }

    // ---------------- transposes
    const float* W;
    __hip_bfloat16* Wt;
    int Kd, Jd, j0, k0;
    bool doScale;
    int tb = bid - 2048;
    if (tb < 1024) {
        W = W1; Wt = W1T; Kd = N_DIM; Jd = H1_DIM;
        j0 = (tb & 31) * 64; k0 = (tb >> 5) * 64; doScale = true;
        // block-redundant softmax over att_w[0..2047]
        float mx = -1e30f;
#pragma unroll
        for (int i = 0; i < 8; ++i) mx = fmaxf(mx, aw[t + i * 256]);
#pragma unroll
        for (int off = 32; off; off >>= 1) mx = fmaxf(mx, __shfl_xor(mx, off, 64));
        if ((t & 63) == 0) red[t >> 6] = mx;
        __syncthreads();
        float M = fmaxf(fmaxf(red[0], red[1]), fmaxf(red[2], red[3]));
        float sm = 0.f;
#pragma unroll
        for (int i = 0; i < 8; ++i) sm += expf(aw[t + i * 256] - M);
#pragma unroll
        for (int off = 32; off; off >>= 1) sm += __shfl_xor(sm, off, 64);
        if ((t & 63) == 0) red[4 + (t >> 6)] = sm;
        __syncthreads();
        float invS = 1.f / (red[4] + red[5] + red[6] + red[7]);
        if (t < 64) scl[t] = expf(aw[k0 + t] - M) * invS;
        __syncthreads();
    } else {
        int b2 = tb - 1024;
        W = W2; Wt = W2T; Kd = H1_DIM; Jd = H2_DIM;
        j0 = (b2 & 7) * 64; k0 = (b2 >> 3) * 64; doScale = false;
    }
#pragma unroll
    for (int p = 0; p < 16; ++p) {
        int r = (t >> 6) + p * 4;
        float v = W[(size_t)(k0 + r) * Jd + j0 + (t & 63)];
        if (doScale) v *= scl[r];
        tile[r][t & 63] = v;
    }
    __syncthreads();
#pragma unroll
    for (int p = 0; p < 8; ++p) {
        int jr = (t >> 5) + p * 8;
        int kc = (t & 31) * 2;
        ushort2 pk;
        pk.x = f2bf(tile[kc][jr]);
        pk.y = f2bf(tile[kc + 1][jr]);
        *(ushort2*)(Wt + (size_t)(j0 + jr) * Kd + k0 + kc) = pk;
    }
}

// ================================================================ GEMM1 (+BN1 stats)
// 64x128 tile, 8 waves (2x4, each 32x32), BK=64, 2-phase double-buffered
// global_load_lds staging, XOR-swizzled LDS, grid (16,16)=256 -> 1 block/CU.
// Staged traffic 192MB (vs 256MB at 64x64). Epilogue: column sum/sumsq -> ps/pq[bx][N].
__global__ __launch_bounds__(512) void gemm1_stats(
        const __hip_bfloat16* __restrict__ A, const __hip_bfloat16* __restrict__ Bt,
        __hip_bfloat16* __restrict__ C, float* __restrict__ ps, float* __restrict__ pq,
        int N, int K) {
    __shared__ __hip_bfloat16 A_s[2][64 * 64];
    __shared__ __hip_bfloat16 B_s[2][128 * 64];
    __shared__ float rs[2][128], rq[2][128];

    // XCD-aware bijective block swizzle (256 blocks)
    int bid = blockIdx.y * 16 + blockIdx.x;
    int wg  = (bid & 7) * 32 + (bid >> 3);
    int bx  = wg & 15, by = wg >> 4;

    int tid = threadIdx.x, lane = tid & 63, wave = tid >> 6;
    int wr = wave >> 2, wc = wave & 3;
    int rbase = bx * 64, cbase = by * 128;
    int l15 = lane & 15, kq = lane >> 4;

    v4f acc[2][2] = {};

    auto stage = [&](int buf, int kt) {
        int k0 = kt << 6;
        {
            int s = tid;                       // 512 slots of 16B = 64 rows x 8 chunks
            int row = s >> 3, cg = (s & 7) ^ (row & 7);
            GLOAD_LDS16(A + (size_t)(rbase + row) * K + k0 + cg * 8, (char*)A_s[buf] + s * 16);
        }
#pragma unroll
        for (int i = 0; i < 2; ++i) {          // 1024 slots = 128 rows x 8 chunks
            int s = tid + i * 512;
            int row = s >> 3, cg = (s & 7) ^ (row & 7);
            GLOAD_LDS16(Bt + (size_t)(cbase + row) * K + k0 + cg * 8, (char*)B_s[buf] + s * 16);
        }
    };

    const int nkt = K >> 6;
    stage(0, 0);
    __syncthreads();
    int cur = 0;
    for (int kt = 0; kt < nkt; ++kt) {
        if (kt + 1 < nkt) stage(cur ^ 1, kt + 1);
#pragma unroll
        for (int kc = 0; kc < 2; ++kc) {
            v8s af[2], bfv[2];
#pragma unroll
            for (int m = 0; m < 2; ++m) {
                int row = wr * 32 + m * 16 + l15;
                int off = row * 128 + ((((kc << 2) + kq) ^ (row & 7)) << 4);
                af[m] = *(const v8s*)((const char*)A_s[cur] + off);
            }
#pragma unroll
            for (int n = 0; n < 2; ++n) {
                int row = wc * 32 + n * 16 + l15;
                int off = row * 128 + ((((kc << 2) + kq) ^ (row & 7)) << 4);
                bfv[n] = *(const v8s*)((const char*)B_s[cur] + off);
            }
            __builtin_amdgcn_s_setprio(1);
#pragma unroll
            for (int m = 0; m < 2; ++m)
#pragma unroll
                for (int n = 0; n < 2; ++n)
                    acc[m][n] = __builtin_amdgcn_mfma_f32_16x16x32_bf16(af[m], bfv[n],
                                                                        acc[m][n], 0, 0, 0);
            __builtin_amdgcn_s_setprio(0);
        }
        __syncthreads();
        cur ^= 1;
    }

    // ---- C write (bf16)
    int crow = kq * 4;
#pragma unroll
    for (int m = 0; m < 2; ++m)
#pragma unroll
        for (int n = 0; n < 2; ++n) {
            int r = rbase + wr * 32 + m * 16 + crow;
            int c = cbase + wc * 32 + n * 16 + l15;
#pragma unroll
            for (int i = 0; i < 4; ++i)
                C[(size_t)(r + i) * N + c] = __float2bfloat16(acc[m][n][i]);
        }

    // ---- fused column stats
    float cs[2], cq[2];
#pragma unroll
    for (int n = 0; n < 2; ++n) {
        cs[n] = 0.f; cq[n] = 0.f;
#pragma unroll
        for (int m = 0; m < 2; ++m)
#pragma unroll
            for (int i = 0; i < 4; ++i) {
                float v = acc[m][n][i];
                cs[n] += v; cq[n] += v * v;
            }
#pragma unroll
        for (int off = 16; off <= 32; off <<= 1) {
            cs[n] += __shfl_xor(cs[n], off, 64);
            cq[n] += __shfl_xor(cq[n], off, 64);
        }
    }
    if (lane < 16) {
#pragma unroll
        for (int n = 0; n < 2; ++n) {
            rs[wr][wc * 32 + n * 16 + lane] = cs[n];
            rq[wr][wc * 32 + n * 16 + lane] = cq[n];
        }
    }
    __syncthreads();
    if (tid < 128) {
        ps[(size_t)bx * N + cbase + tid] = rs[0][tid] + rs[1][tid];
        pq[(size_t)bx * N + cbase + tid] = rq[0][tid] + rq[1][tid];
    }
}

// ================================================================ GEMM2 (+BN2 stats)
// 64 x BN_T tile, BK=128, same structure as before.
template<int BN_T, int TT, typename OutT>
__global__ __launch_bounds__(TT) void gemm_stats(
        const __hip_bfloat16* __restrict__ A, const __hip_bfloat16* __restrict__ Bt,
        OutT* __restrict__ C, float* __restrict__ ps, float* __restrict__ pq,
        int N, int K) {
    constexpr int WC = BN_T / 32;
    constexpr int WR = TT / 64 / WC;
    __shared__ __hip_bfloat16 A_s[2][64 * 128];
    __shared__ __hip_bfloat16 B_s[2][BN_T * 128];
    __shared__ float rs[WR][BN_T], rq[WR][BN_T];

    int nwg = gridDim.x * gridDim.y;
    int bid = blockIdx.y * gridDim.x + blockIdx.x;
    int cpx = nwg >> 3;
    int wg  = (bid & 7) * cpx + (bid >> 3);
    int bx  = wg % gridDim.x, by = wg / gridDim.x;

    int tid = threadIdx.x, lane = tid & 63, wave = tid >> 6;
    int wr = wave / WC, wc = wave % WC;
    int rbase = bx * 64, cbase = by * BN_T;
    int l15 = lane & 15, kq = lane >> 4;

    v4f acc[2][2] = {};

    auto stage = [&](int buf, int kt) {
        int k0 = kt << 7;
#pragma unroll
        for (int i = 0; i < 1024 / TT; ++i) {
            int s = tid + i * TT;
            int row = s >> 4, cg = (s & 15) ^ (row & 15);
            GLOAD_LDS16(A + (size_t)(rbase + row) * K + k0 + cg * 8, (char*)A_s[buf] + s * 16);
        }
#pragma unroll
        for (int i = 0; i < BN_T * 16 / TT; ++i) {
            int s = tid + i * TT;
            int row = s >> 4, cg = (s & 15) ^ (row & 15);
            GLOAD_LDS16(Bt + (size_t)(cbase + row) * K + k0 + cg * 8, (char*)B_s[buf] + s * 16);
        }
    };

    const int nkt = K >> 7;
    stage(0, 0);
    __syncthreads();
    int cur = 0;
    for (int kt = 0; kt < nkt; ++kt) {
        if (kt + 1 < nkt) stage(cur ^ 1, kt + 1);
#pragma unroll
        for (int kc = 0; kc < 4; ++kc) {
            v8s af[2], bfv[2];
#pragma unroll
            for (int m = 0; m < 2; ++m) {
                int row = wr * 32 + m * 16 + l15;
                int off = row * 256 + (((kc * 4 + kq) ^ (row & 15)) << 4);
                af[m] = *(const v8s*)((const char*)A_s[cur] + off);
            }
#pragma unroll
            for (int n = 0; n < 2; ++n) {
                int row = wc * 32 + n * 16 + l15;
                int off = row * 256 + (((kc * 4 + kq) ^ (row & 15)) << 4);
                bfv[n] = *(const v8s*)((const char*)B_s[cur] + off);
            }
            __builtin_amdgcn_s_setprio(1);
#pragma unroll
            for (int m = 0; m < 2; ++m)
#pragma unroll
                for (int n = 0; n < 2; ++n)
                    acc[m][n] = __builtin_amdgcn_mfma_f32_16x16x32_bf16(af[m], bfv[n],
                                                                        acc[m][n], 0, 0, 0);
            __builtin_amdgcn_s_setprio(0);
        }
        __syncthreads();
        cur ^= 1;
    }

    int crow = kq * 4;
#pragma unroll
    for (int m = 0; m < 2; ++m)
#pragma unroll
        for (int n = 0; n < 2; ++n) {
            int r = rbase + wr * 32 + m * 16 + crow;
            int c = cbase + wc * 32 + n * 16 + l15;
#pragma unroll
            for (int i = 0; i < 4; ++i) {
                float v = acc[m][n][i];
                if constexpr (sizeof(OutT) == 2)
                    ((__hip_bfloat16*)C)[(size_t)(r + i) * N + c] = __float2bfloat16(v);
                else
                    ((float*)C)[(size_t)(r + i) * N + c] = v;
            }
        }

    float cs[2], cq[2];
#pragma unroll
    for (int n = 0; n < 2; ++n) {
        cs[n] = 0.f; cq[n] = 0.f;
#pragma unroll
        for (int m = 0; m < 2; ++m)
#pragma unroll
            for (int i = 0; i < 4; ++i) {
                float v = acc[m][n][i];
                cs[n] += v; cq[n] += v * v;
            }
#pragma unroll
        for (int off = 16; off <= 32; off <<= 1) {
            cs[n] += __shfl_xor(cs[n], off, 64);
            cq[n] += __shfl_xor(cq[n], off, 64);
        }
    }
    if (lane < 16) {
#pragma unroll
        for (int n = 0; n < 2; ++n) {
            rs[wr][wc * 32 + n * 16 + lane] = cs[n];
            rq[wr][wc * 32 + n * 16 + lane] = cq[n];
        }
    }
    __syncthreads();
    if (tid < BN_T) {
        float s = 0.f, q = 0.f;
#pragma unroll
        for (int w = 0; w < WR; ++w) { s += rs[w][tid]; q += rq[w][tid]; }
        ps[(size_t)bx * N + cbase + tid] = s;
        pq[(size_t)bx * N + cbase + tid] = q;
    }
}

// ------------------------------------------------ BN1 finalize (block-redundant) + apply + lrelu
__global__ __launch_bounds__(256) void bn_apply_fused(
        const __hip_bfloat16* __restrict__ hpre,
        const float* __restrict__ ps, const float* __restrict__ pq,
        const float* __restrict__ gamma, const float* __restrict__ beta,
        __hip_bfloat16* __restrict__ o) {
    __shared__ float scl[H1_DIM], shf[H1_DIM];
    int t = threadIdx.x;
#pragma unroll
    for (int p = 0; p < 8; ++p) {
        int c = t + p * 256;
        float s = 0.f, q = 0.f;
#pragma unroll
        for (int i = 0; i < 16; ++i) {
            s += ps[i * H1_DIM + c];
            q += pq[i * H1_DIM + c];
        }
        float mu = s * (1.f / B_DIM);
        float var = fmaxf(q * (1.f / B_DIM) - mu * mu, 0.f);
        float rsv = rsqrtf(var + BN_EPS);
        float sc = rsv * gamma[c];
        scl[c] = sc;
        shf[c] = beta[c] - mu * sc;
    }
    __syncthreads();
    int j = t * 8;
    float4 sc0 = *(const float4*)&scl[j];
    float4 sc1 = *(const float4*)&scl[j + 4];
    float4 sh0 = *(const float4*)&shf[j];
    float4 sh1 = *(const float4*)&shf[j + 4];
#pragma unroll
    for (int rr = 0; rr < 8; ++rr) {
        size_t base = (size_t)(blockIdx.x * 8 + rr) * H1_DIM + j;
        v8s v = *(const v8s*)(hpre + base);
        v8s pk;
        pk[0] = (short)f2bf(lrelu_f(bf2f((unsigned short)v[0]) * sc0.x + sh0.x));
        pk[1] = (short)f2bf(lrelu_f(bf2f((unsigned short)v[1]) * sc0.y + sh0.y));
        pk[2] = (short)f2bf(lrelu_f(bf2f((unsigned short)v[2]) * sc0.z + sh0.z));
        pk[3] = (short)f2bf(lrelu_f(bf2f((unsigned short)v[3]) * sc0.w + sh0.w));
        pk[4] = (short)f2bf(lrelu_f(bf2f((unsigned short)v[4]) * sc1.x + sh1.x));
        pk[5] = (short)f2bf(lrelu_f(bf2f((unsigned short)v[5]) * sc1.y + sh1.y));
        pk[6] = (short)f2bf(lrelu_f(bf2f((unsigned short)v[6]) * sc1.z + sh1.z));
        pk[7] = (short)f2bf(lrelu_f(bf2f((unsigned short)v[7]) * sc1.w + sh1.w));
        *(v8s*)(o + base) = pk;
    }
}

// ------------------------------------------------ BN2 finalize (block-redundant) + lrelu + dot(Wo)+bo
__global__ __launch_bounds__(256) void bn_dot_fused(
        const float* __restrict__ h2,
        const float* __restrict__ ps, const float* __restrict__ pq,
        const float* __restrict__ gamma, const float* __restrict__ beta,
        const float* __restrict__ Wo, const float* __restrict__ bo,
        float* __restrict__ out) {
    __shared__ float scl[H2_DIM], shf[H2_DIM];
    __shared__ float red[4][4];
    int t = threadIdx.x;
#pragma unroll
    for (int p = 0; p < 2; ++p) {
        int c = t + p * 256;
        float s = 0.f, q = 0.f;
#pragma unroll
        for (int i = 0; i < 16; ++i) {
            s += ps[i * H2_DIM + c];
            q += pq[i * H2_DIM + c];
        }
        float mu = s * (1.f / B_DIM);
        float var = fmaxf(q * (1.f / B_DIM) - mu * mu, 0.f);
        float rsv = rsqrtf(var + BN_EPS);
        float sc = rsv * gamma[c];
        scl[c] = sc;
        shf[c] = beta[c] - mu * sc;
    }
    __syncthreads();
    float accv[4];
#pragma unroll
    for (int r = 0; r < 4; ++r) {
        int b = blockIdx.x * 4 + r;
        float s = 0.f;
#pragma unroll
        for (int p = 0; p < 2; ++p) {
            int jj = t + p * 256;
            float v = lrelu_f(h2[(size_t)b * H2_DIM + jj] * scl[jj] + shf[jj]);
            s += v * Wo[jj];
        }
#pragma unroll
        for (int off = 32; off; off >>= 1) s += __shfl_down(s, off, 64);
        accv[r] = s;
    }
    if ((t & 63) == 0) {
#pragma unroll
        for (int r = 0; r < 4; ++r) red[t >> 6][r] = accv[r];
    }
    __syncthreads();
    if (t < 4)
        out[blockIdx.x * 4 + t] = red[0][t] + red[1][t] + red[2][t] + red[3][t] + bo[0];
}

// ================================================================ host
extern "C" void kernel_launch(void* const* d_in, const int* in_sizes, int n_in,
                              void* d_out, int out_size, void* d_ws, size_t ws_size,
                              hipStream_t stream) {
    const float* x     = (const float*)d_in[0];
    const float* Wg    = (const float*)d_in[1];
    const float* bg    = (const float*)d_in[2];
    const float* att_w = (const float*)d_in[3];
    const float* W1    = (const float*)d_in[4];
    const float* gamma1 = (const float*)d_in[6];
    const float* beta1  = (const float*)d_in[7];
    const float* W2    = (const float*)d_in[8];
    const float* gamma2 = (const float*)d_in[10];
    const float* beta2  = (const float*)d_in[11];
    const float* Wo    = (const float*)d_in[12];
    const float* bo    = (const float*)d_in[13];
    float* out = (float*)d_out;

    char* ws = (char*)d_ws;
    size_t off = 0;
    auto alloc = [&](size_t bytes) {
        void* p = ws + off;
        off = (off + bytes + 255) & ~(size_t)255;
        return p;
    };
    __hip_bfloat16* W1T    = (__hip_bfloat16*)alloc((size_t)H1_DIM * N_DIM * 2);
    __hip_bfloat16* W2T    = (__hip_bfloat16*)alloc((size_t)H2_DIM * H1_DIM * 2);
    __hip_bfloat16* g      = (__hip_bfloat16*)alloc((size_t)B_DIM * N_DIM * 2);
    __hip_bfloat16* h1pre  = (__hip_bfloat16*)alloc((size_t)B_DIM * H1_DIM * 2);
    __hip_bfloat16* h1     = (__hip_bfloat16*)alloc((size_t)B_DIM * H1_DIM * 2);
    float*          h2raw  = (float*)alloc((size_t)B_DIM * H2_DIM * 4);
    float*          ps     = (float*)alloc(16 * H1_DIM * 4);
    float*          pq     = (float*)alloc(16 * H1_DIM * 4);
    (void)ws_size; (void)in_sizes; (void)n_in; (void)out_size;

    // 1. prep: group_linear (2048 blocks) + softmax/W1T (1024) + W2T (256) in one launch
    prep_kernel<<<dim3(2048 + 1024 + 256), 256, 0, stream>>>(x, Wg, bg, g,
                                                             W1, W2, att_w, W1T, W2T);
    // 2. GEMM1 (+BN1 stats): h1pre = bf16(g @ (att*W1)), 64x128 tiles, 256 blocks
    gemm1_stats<<<dim3(16, 16), 512, 0, stream>>>(g, W1T, h1pre, ps, pq, H1_DIM, N_DIM);
    // 3. BN1 finalize + apply + lrelu -> h1 bf16
    bn_apply_fused<<<dim3(B_DIM / 8), 256, 0, stream>>>(h1pre, ps, pq, gamma1, beta1, h1);
    // 4. GEMM2 (+BN2 stats): h2raw = h1 @ W2   (64x32 tiles, 256 blocks)
    gemm_stats<32, 128, float><<<dim3(B_DIM / 64, H2_DIM / 32), 128, 0, stream>>>(
        h1, W2T, h2raw, ps, pq, H2_DIM, H1_DIM);
    // 5. BN2 finalize + lrelu + dot(Wo) + bo -> out [B]
    bn_dot_fused<<<dim3(B_DIM / 4), 256, 0, stream>>>(h2raw, ps, pq, gamma2, beta2, Wo, bo, out);
}

// Round 8
// 104.268 us; speedup vs baseline: 1.0997x; 1.0997x over previous
//
#include <hip/hip_runtime.h>
#include <hip/hip_bf16.h>

#define B_DIM   1024
#define N_DIM   2048
#define G_DIM   32
#define H1_DIM  2048
#define H2_DIM  512
#define BN_EPS  1e-5f
#define SLOPE   0.05f

typedef short v8s __attribute__((ext_vector_type(8)));
typedef float v4f __attribute__((ext_vector_type(4)));

__device__ __forceinline__ float lrelu_f(float v) { return v >= 0.f ? v : SLOPE * v; }
__device__ __forceinline__ float bf2f(unsigned short u) {
    union { unsigned int i; float f; } c; c.i = ((unsigned int)u) << 16; return c.f;
}
__device__ __forceinline__ unsigned short f2bf(float f) {
    __hip_bfloat16 h = __float2bfloat16(f);
    return *(unsigned short*)&h;
}

// async global->LDS, 16B per lane, linear LDS dest (wave-uniform base + lane*16)
#define GLOAD_LDS16(gp, lp)                                                              \
    __builtin_amdgcn_global_load_lds(                                                    \
        (const __attribute__((address_space(1))) unsigned int*)(gp),                     \
        (__attribute__((address_space(3))) unsigned int*)(lp), 16, 0, 0)

// ================================================================ prep kernel
// bid < 2048          : group_linear  g[b][n] = lrelu(dot(x[b,n*32:], Wg[n]) + bg[n])
// 2048 <= bid < 3072  : W1 [N][H1] -> W1T [H1][N] bf16, rows scaled by softmax(att_w)
// bid >= 3072         : W2 [H1][H2] -> W2T [H2][H1] bf16
__global__ __launch_bounds__(256) void prep_kernel(
        const float* __restrict__ x, const float* __restrict__ Wg,
        const float* __restrict__ bg, __hip_bfloat16* __restrict__ g,
        const float* __restrict__ W1, const float* __restrict__ W2,
        const float* __restrict__ aw,
        __hip_bfloat16* __restrict__ W1T, __hip_bfloat16* __restrict__ W2T) {
    __shared__ float tile[64][65];
    __shared__ float red[8];
    __shared__ float scl[64];
    int t = threadIdx.x;
    int bid = blockIdx.x;

    if (bid < 2048) {
        int brow = bid >> 4;
        int seg = bid & 15;
        int gl = t >> 1, half = t & 1;
        int n = seg * 128 + gl;
        float4 wv[4];
        const float4* wsrc = (const float4*)(Wg + (size_t)n * 32 + half * 16);
#pragma unroll
        for (int q = 0; q < 4; ++q) wv[q] = wsrc[q];
        float bgv = bg[n];
#pragma unroll
        for (int bb = 0; bb < 8; ++bb) {
            int b = brow * 8 + bb;
            const float4* xr = (const float4*)(x + (size_t)b * (N_DIM * G_DIM) +
                                               (size_t)n * 32 + half * 16);
            float s = 0.f;
#pragma unroll
            for (int q = 0; q < 4; ++q) {
                float4 v = xr[q];
                s += v.x * wv[q].x + v.y * wv[q].y + v.z * wv[q].z + v.w * wv[q].w;
            }
            s += __shfl_xor(s, 1, 64);
            if (half == 0)
                g[(size_t)b * N_DIM + n] = __float2bfloat16(lrelu_f(s + bgv));
        }
        return;
    }

    const float* W;
    __hip_bfloat16* Wt;
    int Kd, Jd, j0, k0;
    bool doScale;
    int tb = bid - 2048;
    if (tb < 1024) {
        W = W1; Wt = W1T; Kd = N_DIM; Jd = H1_DIM;
        j0 = (tb & 31) * 64; k0 = (tb >> 5) * 64; doScale = true;
        float mx = -1e30f;
#pragma unroll
        for (int i = 0; i < 8; ++i) mx = fmaxf(mx, aw[t + i * 256]);
#pragma unroll
        for (int off = 32; off; off >>= 1) mx = fmaxf(mx, __shfl_xor(mx, off, 64));
        if ((t & 63) == 0) red[t >> 6] = mx;
        __syncthreads();
        float M = fmaxf(fmaxf(red[0], red[1]), fmaxf(red[2], red[3]));
        float sm = 0.f;
#pragma unroll
        for (int i = 0; i < 8; ++i) sm += expf(aw[t + i * 256] - M);
#pragma unroll
        for (int off = 32; off; off >>= 1) sm += __shfl_xor(sm, off, 64);
        if ((t & 63) == 0) red[4 + (t >> 6)] = sm;
        __syncthreads();
        float invS = 1.f / (red[4] + red[5] + red[6] + red[7]);
        if (t < 64) scl[t] = expf(aw[k0 + t] - M) * invS;
        __syncthreads();
    } else {
        int b2 = tb - 1024;
        W = W2; Wt = W2T; Kd = H1_DIM; Jd = H2_DIM;
        j0 = (b2 & 7) * 64; k0 = (b2 >> 3) * 64; doScale = false;
    }
#pragma unroll
    for (int p = 0; p < 16; ++p) {
        int r = (t >> 6) + p * 4;
        float v = W[(size_t)(k0 + r) * Jd + j0 + (t & 63)];
        if (doScale) v *= scl[r];
        tile[r][t & 63] = v;
    }
    __syncthreads();
#pragma unroll
    for (int p = 0; p < 8; ++p) {
        int jr = (t >> 5) + p * 8;
        int kc = (t & 31) * 2;
        ushort2 pk;
        pk.x = f2bf(tile[kc][jr]);
        pk.y = f2bf(tile[kc + 1][jr]);
        *(ushort2*)(Wt + (size_t)(j0 + jr) * Kd + k0 + kc) = pk;
    }
}

// ================================================================ GEMM1 (+BN1 stats)
// Round-5 proven config: 64x64 tile, 4 waves, BK=128, grid (16,32)=512 -> 2 blocks/CU.
// XOR-swizzled LDS (chunk^(row&15)), setprio around MFMA, XCD-chunk block swizzle.
__global__ __launch_bounds__(256) void gemm1_stats(
        const __hip_bfloat16* __restrict__ A, const __hip_bfloat16* __restrict__ Bt,
        __hip_bfloat16* __restrict__ C, float* __restrict__ ps, float* __restrict__ pq) {
    __shared__ __hip_bfloat16 A_s[2][64 * 128];
    __shared__ __hip_bfloat16 B_s[2][64 * 128];
    __shared__ float rs[2][64], rq[2][64];

    int bid = blockIdx.x;                       // 512 blocks
    int wg  = (bid & 7) * 64 + (bid >> 3);      // XCD-aware bijective swizzle
    int bx  = wg & 15, by = wg >> 4;            // 16 row-tiles x 32 col-tiles

    int tid = threadIdx.x, lane = tid & 63, wave = tid >> 6;
    int wr = wave >> 1, wc = wave & 1;
    int rbase = bx * 64, cbase = by * 64;
    int l15 = lane & 15, kq = lane >> 4;

    v4f acc[2][2] = {};

    auto stage = [&](int buf, int kt) {
        int k0 = kt << 7;
#pragma unroll
        for (int i = 0; i < 4; ++i) {
            int s = tid + i * 256;
            int row = s >> 4, cg = (s & 15) ^ (row & 15);
            GLOAD_LDS16(A + (size_t)(rbase + row) * N_DIM + k0 + cg * 8,
                        (char*)A_s[buf] + s * 16);
        }
#pragma unroll
        for (int i = 0; i < 4; ++i) {
            int s = tid + i * 256;
            int row = s >> 4, cg = (s & 15) ^ (row & 15);
            GLOAD_LDS16(Bt + (size_t)(cbase + row) * N_DIM + k0 + cg * 8,
                        (char*)B_s[buf] + s * 16);
        }
    };

    stage(0, 0);
    __syncthreads();
    int cur = 0;
    for (int kt = 0; kt < 16; ++kt) {
        if (kt + 1 < 16) stage(cur ^ 1, kt + 1);
#pragma unroll
        for (int kc = 0; kc < 4; ++kc) {
            v8s af[2], bfv[2];
#pragma unroll
            for (int m = 0; m < 2; ++m) {
                int row = wr * 32 + m * 16 + l15;
                int off = row * 256 + (((kc * 4 + kq) ^ (row & 15)) << 4);
                af[m] = *(const v8s*)((const char*)A_s[cur] + off);
            }
#pragma unroll
            for (int n = 0; n < 2; ++n) {
                int row = wc * 32 + n * 16 + l15;
                int off = row * 256 + (((kc * 4 + kq) ^ (row & 15)) << 4);
                bfv[n] = *(const v8s*)((const char*)B_s[cur] + off);
            }
            __builtin_amdgcn_s_setprio(1);
#pragma unroll
            for (int m = 0; m < 2; ++m)
#pragma unroll
                for (int n = 0; n < 2; ++n)
                    acc[m][n] = __builtin_amdgcn_mfma_f32_16x16x32_bf16(af[m], bfv[n],
                                                                        acc[m][n], 0, 0, 0);
            __builtin_amdgcn_s_setprio(0);
        }
        __syncthreads();
        cur ^= 1;
    }

    int crow = kq * 4;
#pragma unroll
    for (int m = 0; m < 2; ++m)
#pragma unroll
        for (int n = 0; n < 2; ++n) {
            int r = rbase + wr * 32 + m * 16 + crow;
            int c = cbase + wc * 32 + n * 16 + l15;
#pragma unroll
            for (int i = 0; i < 4; ++i)
                C[(size_t)(r + i) * H1_DIM + c] = __float2bfloat16(acc[m][n][i]);
        }

    float cs[2], cq[2];
#pragma unroll
    for (int n = 0; n < 2; ++n) {
        cs[n] = 0.f; cq[n] = 0.f;
#pragma unroll
        for (int m = 0; m < 2; ++m)
#pragma unroll
            for (int i = 0; i < 4; ++i) {
                float v = acc[m][n][i];
                cs[n] += v; cq[n] += v * v;
            }
#pragma unroll
        for (int off = 16; off <= 32; off <<= 1) {
            cs[n] += __shfl_xor(cs[n], off, 64);
            cq[n] += __shfl_xor(cq[n], off, 64);
        }
    }
    if (lane < 16) {
#pragma unroll
        for (int n = 0; n < 2; ++n) {
            rs[wr][wc * 32 + n * 16 + lane] = cs[n];
            rq[wr][wc * 32 + n * 16 + lane] = cq[n];
        }
    }
    __syncthreads();
    if (tid < 64) {
        ps[(size_t)bx * H1_DIM + cbase + tid] = rs[0][tid] + rs[1][tid];
        pq[(size_t)bx * H1_DIM + cbase + tid] = rq[0][tid] + rq[1][tid];
    }
}

// ================================================================ GEMM2 with BN1 folded
// 64x32 tile, 4 waves (each 16 rows x 32 cols), BK=128, grid (16,16)=256 blocks.
// Prologue: block-redundant BN1 finalize from ps1/pq1 -> scl/shf[2048] in LDS.
// A-staging: reg-load h1pre bf16, apply scale/shift+lrelu, bf16, swizzled ds_write.
// B-staging: global_load_lds. Epilogue: BN2 partial stats.
__global__ __launch_bounds__(256) void gemm2_bn1(
        const __hip_bfloat16* __restrict__ h1pre, const __hip_bfloat16* __restrict__ W2T,
        float* __restrict__ h2raw,
        const float* __restrict__ ps1, const float* __restrict__ pq1,
        const float* __restrict__ gamma1, const float* __restrict__ beta1,
        float* __restrict__ ps2, float* __restrict__ pq2) {
    __shared__ float scl[H1_DIM], shf[H1_DIM];
    __shared__ __hip_bfloat16 A2[2][64 * 128];
    __shared__ __hip_bfloat16 B2[2][32 * 128];
    __shared__ float rs2[4][32], rq2[4][32];

    int tid = threadIdx.x, lane = tid & 63, wave = tid >> 6;
    int l15 = lane & 15, kq = lane >> 4;

    // BN1 finalize (block-redundant, 8 cols/thread from 16 partials)
#pragma unroll
    for (int p = 0; p < 8; ++p) {
        int c = tid + p * 256;
        float s = 0.f, q = 0.f;
#pragma unroll
        for (int i = 0; i < 16; ++i) {
            s += ps1[i * H1_DIM + c];
            q += pq1[i * H1_DIM + c];
        }
        float mu = s * (1.f / B_DIM);
        float var = fmaxf(q * (1.f / B_DIM) - mu * mu, 0.f);
        float rsv = rsqrtf(var + BN_EPS);
        float sc = rsv * gamma1[c];
        scl[c] = sc;
        shf[c] = beta1[c] - mu * sc;
    }
    __syncthreads();

    int bid = blockIdx.x;
    int wg = (bid & 7) * 32 + (bid >> 3);       // XCD swizzle, 256 blocks
    int bxx = wg & 15, byy = wg >> 4;           // 16 row-tiles x 16 col-tiles
    int rb = bxx * 64, cb = byy * 32;

    v4f acc2[2] = {};

    auto stageA2 = [&](int buf, int kt) {       // reg-staged + BN+lrelu + swizzled ds_write
        int k0 = kt << 7;
#pragma unroll
        for (int i = 0; i < 4; ++i) {
            int s = tid + i * 256;
            int row = s >> 4, cc = s & 15;
            v8s hv = *(const v8s*)(h1pre + (size_t)(rb + row) * H1_DIM + k0 + cc * 8);
            int kk = k0 + cc * 8;
            float4 s0 = *(const float4*)&scl[kk];
            float4 s1 = *(const float4*)&scl[kk + 4];
            float4 f0 = *(const float4*)&shf[kk];
            float4 f1 = *(const float4*)&shf[kk + 4];
            v8s pk;
            pk[0] = (short)f2bf(lrelu_f(bf2f((unsigned short)hv[0]) * s0.x + f0.x));
            pk[1] = (short)f2bf(lrelu_f(bf2f((unsigned short)hv[1]) * s0.y + f0.y));
            pk[2] = (short)f2bf(lrelu_f(bf2f((unsigned short)hv[2]) * s0.z + f0.z));
            pk[3] = (short)f2bf(lrelu_f(bf2f((unsigned short)hv[3]) * s0.w + f0.w));
            pk[4] = (short)f2bf(lrelu_f(bf2f((unsigned short)hv[4]) * s1.x + f1.x));
            pk[5] = (short)f2bf(lrelu_f(bf2f((unsigned short)hv[5]) * s1.y + f1.y));
            pk[6] = (short)f2bf(lrelu_f(bf2f((unsigned short)hv[6]) * s1.z + f1.z));
            pk[7] = (short)f2bf(lrelu_f(bf2f((unsigned short)hv[7]) * s1.w + f1.w));
            *(v8s*)((char*)A2[buf] + (row * 16 + (cc ^ (row & 15))) * 16) = pk;
        }
    };
    auto stageB2 = [&](int buf, int kt) {
        int k0 = kt << 7;
#pragma unroll
        for (int i = 0; i < 2; ++i) {
            int s = tid + i * 256;
            int row = s >> 4, cg2 = (s & 15) ^ (row & 15);
            GLOAD_LDS16(W2T + (size_t)(cb + row) * H1_DIM + k0 + cg2 * 8,
                        (char*)B2[buf] + s * 16);
        }
    };

    stageB2(0, 0);
    stageA2(0, 0);
    __syncthreads();
    int cur = 0;
    for (int kt = 0; kt < 16; ++kt) {
        if (kt + 1 < 16) { stageB2(cur ^ 1, kt + 1); stageA2(cur ^ 1, kt + 1); }
#pragma unroll
        for (int kc = 0; kc < 4; ++kc) {
            int arow = wave * 16 + l15;
            v8s af = *(const v8s*)((const char*)A2[cur] +
                                   arow * 256 + (((kc * 4 + kq) ^ (arow & 15)) << 4));
            v8s bf0 = *(const v8s*)((const char*)B2[cur] +
                                    l15 * 256 + (((kc * 4 + kq) ^ (l15 & 15)) << 4));
            int brow1 = 16 + l15;
            v8s bf1 = *(const v8s*)((const char*)B2[cur] +
                                    brow1 * 256 + (((kc * 4 + kq) ^ (brow1 & 15)) << 4));
            __builtin_amdgcn_s_setprio(1);
            acc2[0] = __builtin_amdgcn_mfma_f32_16x16x32_bf16(af, bf0, acc2[0], 0, 0, 0);
            acc2[1] = __builtin_amdgcn_mfma_f32_16x16x32_bf16(af, bf1, acc2[1], 0, 0, 0);
            __builtin_amdgcn_s_setprio(0);
        }
        __syncthreads();
        cur ^= 1;
    }

    int crow = kq * 4;
#pragma unroll
    for (int n = 0; n < 2; ++n) {
        int r = rb + wave * 16 + crow;
        int c = cb + n * 16 + l15;
#pragma unroll
        for (int i = 0; i < 4; ++i)
            h2raw[(size_t)(r + i) * H2_DIM + c] = acc2[n][i];
    }

    float cs[2], cq[2];
#pragma unroll
    for (int n = 0; n < 2; ++n) {
        cs[n] = 0.f; cq[n] = 0.f;
#pragma unroll
        for (int i = 0; i < 4; ++i) {
            float v = acc2[n][i];
            cs[n] += v; cq[n] += v * v;
        }
#pragma unroll
        for (int off = 16; off <= 32; off <<= 1) {
            cs[n] += __shfl_xor(cs[n], off, 64);
            cq[n] += __shfl_xor(cq[n], off, 64);
        }
    }
    if (lane < 16) {
#pragma unroll
        for (int n = 0; n < 2; ++n) {
            rs2[wave][n * 16 + lane] = cs[n];
            rq2[wave][n * 16 + lane] = cq[n];
        }
    }
    __syncthreads();
    if (tid < 32) {
        float s = 0.f, q = 0.f;
#pragma unroll
        for (int w = 0; w < 4; ++w) { s += rs2[w][tid]; q += rq2[w][tid]; }
        ps2[(size_t)bxx * H2_DIM + cb + tid] = s;
        pq2[(size_t)bxx * H2_DIM + cb + tid] = q;
    }
}

// ------------------------------------------------ BN2 finalize (block-redundant) + lrelu + dot(Wo)+bo
__global__ __launch_bounds__(256) void bn_dot_fused(
        const float* __restrict__ h2,
        const float* __restrict__ ps, const float* __restrict__ pq,
        const float* __restrict__ gamma, const float* __restrict__ beta,
        const float* __restrict__ Wo, const float* __restrict__ bo,
        float* __restrict__ out) {
    __shared__ float scl[H2_DIM], shf[H2_DIM];
    __shared__ float red[4][4];
    int t = threadIdx.x;
#pragma unroll
    for (int p = 0; p < 2; ++p) {
        int c = t + p * 256;
        float s = 0.f, q = 0.f;
#pragma unroll
        for (int i = 0; i < 16; ++i) {
            s += ps[i * H2_DIM + c];
            q += pq[i * H2_DIM + c];
        }
        float mu = s * (1.f / B_DIM);
        float var = fmaxf(q * (1.f / B_DIM) - mu * mu, 0.f);
        float rsv = rsqrtf(var + BN_EPS);
        float sc = rsv * gamma[c];
        scl[c] = sc;
        shf[c] = beta[c] - mu * sc;
    }
    __syncthreads();
    float accv[4];
#pragma unroll
    for (int r = 0; r < 4; ++r) {
        int b = blockIdx.x * 4 + r;
        float s = 0.f;
#pragma unroll
        for (int p = 0; p < 2; ++p) {
            int jj = t + p * 256;
            float v = lrelu_f(h2[(size_t)b * H2_DIM + jj] * scl[jj] + shf[jj]);
            s += v * Wo[jj];
        }
#pragma unroll
        for (int off = 32; off; off >>= 1) s += __shfl_down(s, off, 64);
        accv[r] = s;
    }
    if ((t & 63) == 0) {
#pragma unroll
        for (int r = 0; r < 4; ++r) red[t >> 6][r] = accv[r];
    }
    __syncthreads();
    if (t < 4)
        out[blockIdx.x * 4 + t] = red[0][t] + red[1][t] + red[2][t] + red[3][t] + bo[0];
}

// ================================================================ host
extern "C" void kernel_launch(void* const* d_in, const int* in_sizes, int n_in,
                              void* d_out, int out_size, void* d_ws, size_t ws_size,
                              hipStream_t stream) {
    const float* x     = (const float*)d_in[0];
    const float* Wg    = (const float*)d_in[1];
    const float* bg    = (const float*)d_in[2];
    const float* att_w = (const float*)d_in[3];
    const float* W1    = (const float*)d_in[4];
    const float* gamma1 = (const float*)d_in[6];
    const float* beta1  = (const float*)d_in[7];
    const float* W2    = (const float*)d_in[8];
    const float* gamma2 = (const float*)d_in[10];
    const float* beta2  = (const float*)d_in[11];
    const float* Wo    = (const float*)d_in[12];
    const float* bo    = (const float*)d_in[13];
    float* out = (float*)d_out;

    char* ws = (char*)d_ws;
    size_t off = 0;
    auto alloc = [&](size_t bytes) {
        void* p = ws + off;
        off = (off + bytes + 255) & ~(size_t)255;
        return p;
    };
    __hip_bfloat16* W1T   = (__hip_bfloat16*)alloc((size_t)H1_DIM * N_DIM * 2);
    __hip_bfloat16* W2T   = (__hip_bfloat16*)alloc((size_t)H2_DIM * H1_DIM * 2);
    __hip_bfloat16* g     = (__hip_bfloat16*)alloc((size_t)B_DIM * N_DIM * 2);
    __hip_bfloat16* h1pre = (__hip_bfloat16*)alloc((size_t)B_DIM * H1_DIM * 2);
    float*          h2raw = (float*)alloc((size_t)B_DIM * H2_DIM * 4);
    float*          ps1   = (float*)alloc(16 * H1_DIM * 4);
    float*          pq1   = (float*)alloc(16 * H1_DIM * 4);
    float*          ps2   = (float*)alloc(16 * H2_DIM * 4);
    float*          pq2   = (float*)alloc(16 * H2_DIM * 4);
    (void)ws_size; (void)in_sizes; (void)n_in; (void)out_size;

    // 1. prep: group_linear (2048 blocks) + softmax/W1T (1024) + W2T (256)
    prep_kernel<<<dim3(2048 + 1024 + 256), 256, 0, stream>>>(x, Wg, bg, g,
                                                             W1, W2, att_w, W1T, W2T);
    // 2. GEMM1 (+BN1 stats): h1pre = bf16(g @ (att*W1)), 64x64 tiles, 512 blocks
    gemm1_stats<<<dim3(512), 256, 0, stream>>>(g, W1T, h1pre, ps1, pq1);
    // 3. GEMM2 with BN1 finalize+apply+lrelu folded into A-staging (+BN2 stats)
    gemm2_bn1<<<dim3(256), 256, 0, stream>>>(h1pre, W2T, h2raw, ps1, pq1,
                                             gamma1, beta1, ps2, pq2);
    // 4. BN2 finalize + lrelu + dot(Wo) + bo -> out [B]
    bn_dot_fused<<<dim3(B_DIM / 4), 256, 0, stream>>>(h2raw, ps2, pq2, gamma2, beta2,
                                                      Wo, bo, out);
}